// Round 1
// baseline (136.832 us; speedup 1.0000x reference)
//
#include <hip/hip_runtime.h>

// D2Q9 MRT (Gram-Schmidt) LBM, 4 fused stream+collide steps on 1024x1024.
//
// Layout strategy:
//   input  f: AoS [X][Y][9] float32 (as given)
//   ws    : SoA 9 planes of [X][Y] for iterations in the middle (coalesced)
//   output  : AoS [X][Y][9] float32
// Streaming (periodic jnp.roll) becomes a gather with &1023 index wrap.
//
// Collision: m = M f; m' = m - (1/tau)(m - meq); f' = Minv m'.
// M's rows are orthogonal with norms [9,6,6,36,36,12,12,4,4], so
// Minv[q][p] = M[p][q]/norm[p]; expanded by hand below (integer weights).

#define NXD 1024
#define NYD 1024
#define NCELL (NXD * NYD)

// TAU=0.6, GX=0, GY=-1e-4  (GX term folds to exact no-op)
constexpr float INV_TAU = (float)(1.0 / 0.6);
constexpr float TGY     = (float)(0.6 * -1e-4);   // TAU*GY

template <bool SRC_AOS, bool DST_AOS>
__global__ __launch_bounds__(256) void lbm_step(const float* __restrict__ src,
                                                float* __restrict__ dst,
                                                const float* __restrict__ wp) {
    const int cell = blockIdx.x * 256 + threadIdx.x;
    const int x = cell >> 10;          // NY = 1024
    const int y = cell & (NYD - 1);
    const int xm = (x + NXD - 1) & (NXD - 1);
    const int xp = (x + 1) & (NXD - 1);
    const int ym = (y + NYD - 1) & (NYD - 1);
    const int yp = (y + 1) & (NYD - 1);

    // learned coefficients (uniform; scalar-loaded, L2-resident)
    const float w0 = wp[0], w1 = wp[1], w2 = wp[2], w3 = wp[3];
    const float w4 = wp[4], w5 = wp[5], w6 = wp[6];

    // --- stream (gather): f_i(x,y) <- f_i(x - ex_i, y - ey_i) ---
    float f0, f1, f2, f3, f4, f5, f6, f7, f8;
    if (SRC_AOS) {
        f0 = src[(x  * NYD + y ) * 9 + 0];
        f1 = src[(xm * NYD + y ) * 9 + 1];
        f2 = src[(x  * NYD + ym) * 9 + 2];
        f3 = src[(xp * NYD + y ) * 9 + 3];
        f4 = src[(x  * NYD + yp) * 9 + 4];
        f5 = src[(xm * NYD + ym) * 9 + 5];
        f6 = src[(xp * NYD + ym) * 9 + 6];
        f7 = src[(xp * NYD + yp) * 9 + 7];
        f8 = src[(xm * NYD + yp) * 9 + 8];
    } else {
        f0 = src[0 * NCELL + x  * NYD + y ];
        f1 = src[1 * NCELL + xm * NYD + y ];
        f2 = src[2 * NCELL + x  * NYD + ym];
        f3 = src[3 * NCELL + xp * NYD + y ];
        f4 = src[4 * NCELL + x  * NYD + yp];
        f5 = src[5 * NCELL + xm * NYD + ym];
        f6 = src[6 * NCELL + xp * NYD + ym];
        f7 = src[7 * NCELL + xp * NYD + yp];
        f8 = src[8 * NCELL + xm * NYD + yp];
    }

    // --- macroscopic fields (mirror reference FP order) ---
    const float rho = f0 + f1 + f2 + f3 + f4 + f5 + f6 + f7 + f8;
    const float jx0 = f1 - f3 + f5 - f6 - f7 + f8;   // sum f*ex
    const float jy0 = f2 - f4 + f5 + f6 - f7 - f8;   // sum f*ey
    const float vx = jx0 / rho;
    const float vy = jy0 / rho;
    // ux = vx + TAU*GX*rho = vx (GX=0); uy = vy + TAU*GY*rho
    const float uy = vy + TGY * rho;
    const float jx = rho * vx;
    const float jy = rho * uy;
    const float j2 = jx * jx + jy * jy;

    // --- raw moments m = M f ---
    const float ax  = f1 + f2 + f3 + f4;       // axis populations
    const float dg  = f5 + f6 + f7 + f8;       // diagonal populations
    const float m3 = -4.f * f0 - ax + 2.f * dg;             // e
    const float m4 =  4.f * f0 - 2.f * ax + dg;             // eps
    const float m5 = -2.f * f1 + 2.f * f3 + f5 - f6 - f7 + f8;  // qx
    const float m6 = -2.f * f2 + 2.f * f4 + f5 + f6 - f7 - f8;  // qy
    const float m7 = f1 - f2 + f3 - f4;                     // pxx
    const float m8 = f5 - f6 + f7 - f8;                     // pxy

    // --- equilibrium moments ---
    const float me3 = w0 * rho + w1 * j2;
    const float me4 = w2 * rho - w3 * j2;
    const float me5 = w4 * jx;
    const float me6 = w4 * jy;
    const float me7 = w5 * (jx * jx - jy * jy);
    const float me8 = w6 * (jx * jy);

    // --- relax: m' = m - (1/tau)(m - meq) ---
    const float mp0 = rho;                                   // meq0 == m0
    const float mp1 = jx0 - INV_TAU * (jx0 - jx);
    const float mp2 = jy0 - INV_TAU * (jy0 - jy);
    const float mp3 = m3  - INV_TAU * (m3 - me3);
    const float mp4 = m4  - INV_TAU * (m4 - me4);
    const float mp5 = m5  - INV_TAU * (m5 - me5);
    const float mp6 = m6  - INV_TAU * (m6 - me6);
    const float mp7 = m7  - INV_TAU * (m7 - me7);
    const float mp8 = m8  - INV_TAU * (m8 - me8);

    // --- back-transform: f' = M^T diag(1/norm) m' ---
    const float s0 = mp0 * (1.f / 9.f);
    const float s1 = mp1 * (1.f / 6.f);
    const float s2 = mp2 * (1.f / 6.f);
    const float s3 = mp3 * (1.f / 36.f);
    const float s4 = mp4 * (1.f / 36.f);
    const float s5 = mp5 * (1.f / 12.f);
    const float s6 = mp6 * (1.f / 12.f);
    const float s7 = mp7 * 0.25f;
    const float s8 = mp8 * 0.25f;

    const float h0 = s0 - s3 - 2.f * s4;   // axis common
    const float g0 = s0 + 2.f * s3 + s4;   // diagonal common

    float fn0 = s0 - 4.f * s3 + 4.f * s4;
    float fn1 = h0 + s1 - 2.f * s5 + s7;
    float fn2 = h0 + s2 - 2.f * s6 - s7;
    float fn3 = h0 - s1 + 2.f * s5 + s7;
    float fn4 = h0 - s2 + 2.f * s6 - s7;
    float fn5 = g0 + s1 + s2 + s5 + s6 + s8;
    float fn6 = g0 - s1 + s2 - s5 + s6 - s8;
    float fn7 = g0 - s1 - s2 - s5 - s6 + s8;
    float fn8 = g0 + s1 - s2 + s5 - s6 - s8;

    if (DST_AOS) {
        float* o = dst + (size_t)(x * NYD + y) * 9;
        o[0] = fn0; o[1] = fn1; o[2] = fn2; o[3] = fn3; o[4] = fn4;
        o[5] = fn5; o[6] = fn6; o[7] = fn7; o[8] = fn8;
    } else {
        const int c = x * NYD + y;
        dst[0 * NCELL + c] = fn0;
        dst[1 * NCELL + c] = fn1;
        dst[2 * NCELL + c] = fn2;
        dst[3 * NCELL + c] = fn3;
        dst[4 * NCELL + c] = fn4;
        dst[5 * NCELL + c] = fn5;
        dst[6 * NCELL + c] = fn6;
        dst[7 * NCELL + c] = fn7;
        dst[8 * NCELL + c] = fn8;
    }
}

extern "C" void kernel_launch(void* const* d_in, const int* in_sizes, int n_in,
                              void* d_out, int out_size, void* d_ws, size_t ws_size,
                              hipStream_t stream) {
    const float* f_in = (const float*)d_in[0];
    const float* w    = (const float*)d_in[1];
    float* out = (float*)d_out;
    float* ws0 = (float*)d_ws;
    const size_t bufBytes = (size_t)NCELL * 9 * sizeof(float);

    dim3 grid(NCELL / 256), block(256);

    if (ws_size >= 2 * bufBytes) {
        float* ws1 = ws0 + (size_t)NCELL * 9;
        lbm_step<true,  false><<<grid, block, 0, stream>>>(f_in, ws0, w);
        lbm_step<false, false><<<grid, block, 0, stream>>>(ws0, ws1, w);
        lbm_step<false, false><<<grid, block, 0, stream>>>(ws1, ws0, w);
        lbm_step<false, true ><<<grid, block, 0, stream>>>(ws0, out, w);
    } else if (ws_size >= bufBytes) {
        // use d_out as the second SoA scratch buffer mid-flight
        lbm_step<true,  false><<<grid, block, 0, stream>>>(f_in, ws0, w);
        lbm_step<false, false><<<grid, block, 0, stream>>>(ws0, out, w);
        lbm_step<false, false><<<grid, block, 0, stream>>>(out, ws0, w);
        lbm_step<false, true ><<<grid, block, 0, stream>>>(ws0, out, w);
    } else {
        // last resort: AoS ping-pong via d_in (harness restores inputs
        // before every timed call) + one async D2D to land in d_out
        float* fin_mut = (float*)d_in[0];
        lbm_step<true, true><<<grid, block, 0, stream>>>(f_in, out, w);
        lbm_step<true, true><<<grid, block, 0, stream>>>(out, fin_mut, w);
        lbm_step<true, true><<<grid, block, 0, stream>>>(fin_mut, out, w);
        lbm_step<true, true><<<grid, block, 0, stream>>>(out, fin_mut, w);
        hipMemcpyAsync(d_out, fin_mut, bufBytes, hipMemcpyDeviceToDevice, stream);
    }
}